// Round 5
// baseline (6082.044 us; speedup 1.0000x reference)
//
#include <hip/hip_runtime.h>

// SimpleLSTM B=128,T=8192,H=96. One block per batch, 384 threads (6 waves).
// R4 post-mortem: 3-phase step (MFMA -> pre_s round-trip -> 96-thread cell
// update) with 2 barriers + per-step global y store = ~1620 cyc/step.
// R5: since every B-frag column holds the same h, all 16 D-columns are
// identical -> each lane (m,quad) of tile mt ALREADY holds gates i,f,g,o of
// cell 4mt+quad in its acc regs. Activation + cell update run in-lane on all
// 6 waves (lane updates cell 16w+4(m&3)+q; c in regs; redundant across
// m-groups; m<4 lanes write h). ONE barrier/step. y is staged in an LDS ring
// (wave5 writes, wave4 flushes 128 at a time) so no per-step vmcnt drain.
//   - W_hh rows PERMUTED: tile mt row m <-> orig row (m&3)*96 + 4mt + (m>>2)
//     => D reg r of (mt,quad) = gate r (i,f,g,o) of cell 4mt+quad.
//   - 25th M-tile row 0 = w_out => y_t = D[0][*] of wave5's extra tile.
// fp16 only on W_hh/w_out/h (MFMA inputs); x, biases, gates, c, y in fp32.

#define T_LEN 8192
#define H_DIM 96
#define NTHR  384   // 6 waves
#define CHUNK 128   // y-ring flush granularity

typedef float    f32x4 __attribute__((ext_vector_type(4)));
typedef _Float16 half8 __attribute__((ext_vector_type(8)));

__device__ __forceinline__ float fast_sigmoid(float v) {
    return 1.0f / (1.0f + __expf(-v));
}
__device__ __forceinline__ float fast_tanh(float v) {
    return 1.0f - 2.0f / (__expf(2.0f * v) + 1.0f);  // stable at +-inf
}

__global__ __launch_bounds__(NTHR, 1) void lstm_mfma2_kernel(
    const float* __restrict__ x,      // [B, T]
    const float* __restrict__ w_ih,   // [4H]
    const float* __restrict__ w_hh,   // [4H, H]
    const float* __restrict__ b_ih,   // [4H]
    const float* __restrict__ b_hh,   // [4H]
    const float* __restrict__ w_out,  // [H]
    const float* __restrict__ b_out,  // [1]
    float* __restrict__ y)            // [B, T]
{
    const int b    = blockIdx.x;
    const int tid  = threadIdx.x;
    const int wave = tid >> 6;
    const int lane = tid & 63;
    const int m    = lane & 15;   // A row within tile / D col
    const int quad = lane >> 4;   // k-group / D row-group

    __shared__ __align__(16) _Float16 h_s[2][H_DIM];     // double-buffered h
    __shared__ __align__(16) float    y_buf[2][CHUNK];   // y staging ring

    // ---- A fragments: wave w owns tiles 4w..4w+3; wave 5 also tile 24 (y).
    // A[m][k]: lane (m,quad) holds k = 32*kt + 8*quad + j.
    const int ntile = (wave == 5) ? 5 : 4;
    f32x4 afr[5][3];
    #pragma unroll
    for (int s = 0; s < 5; ++s) {
        const int mt = (s < 4) ? (4 * wave + s) : 24;
        #pragma unroll
        for (int kt = 0; kt < 3; ++kt) {
            half8 f;
            if (s < ntile) {
                if (mt < 24) {
                    const int orig = (m & 3) * 96 + 4 * mt + (m >> 2);
                    const float* src = w_hh + orig * H_DIM + kt * 32 + quad * 8;
                    #pragma unroll
                    for (int jj = 0; jj < 8; ++jj) f[jj] = (_Float16)src[jj];
                } else {  // y tile: row 0 = w_out, rows 1..15 = 0
                    #pragma unroll
                    for (int jj = 0; jj < 8; ++jj)
                        f[jj] = (m == 0) ? (_Float16)w_out[kt * 32 + quad * 8 + jj]
                                         : (_Float16)0.0f;
                }
            } else {
                #pragma unroll
                for (int jj = 0; jj < 8; ++jj) f[jj] = (_Float16)0.0f;
            }
            afr[s][kt] = __builtin_bit_cast(f32x4, f);
            asm volatile("" : "+v"(afr[s][kt]));  // pin in VGPRs
        }
    }

    // ---- per-lane cell params: lane updates cell 16w + 4*(m&3) + quad
    const int cell = 16 * wave + 4 * (m & 3) + quad;
    float bias4[4], wih4[4];
    #pragma unroll
    for (int g = 0; g < 4; ++g) {
        bias4[g] = b_ih[g * H_DIM + cell] + b_hh[g * H_DIM + cell];
        wih4[g]  = w_ih[g * H_DIM + cell];
    }
    float c = 0.f;
    const float bout = b_out[0];
    if (tid < H_DIM) h_s[0][tid] = (_Float16)0.0f;
    __syncthreads();

    const float* xrow = x + (size_t)b * T_LEN;
    float*       yrow = y + (size_t)b * T_LEN;
    float x_next = xrow[0];  // uniform address -> scalar load

    // iter it: reads h_{it-1} (h_s[it&1]); makes h_it; y tile -> y_{it-1}.
    // it==T_LEN: flush y_{T-1} into ring; it==T_LEN+1: final ring flush only.
    for (int it = 0; it <= T_LEN + 1; ++it) {
        const int p = it & 1;
        const float x_cur = x_next;
        x_next = xrow[(it + 1 < T_LEN) ? (it + 1) : (T_LEN - 1)];

        f32x4 acc[5];
        if (it <= T_LEN) {
            f32x4 bfr[3];  // B[k][*] = h[k] broadcast into all 16 cols
            #pragma unroll
            for (int kt = 0; kt < 3; ++kt)
                bfr[kt] = *reinterpret_cast<const f32x4*>(&h_s[p][kt * 32 + quad * 8]);
            #pragma unroll
            for (int s = 0; s < 5; ++s) {
                if (s < ntile) {
                    f32x4 a = {0.f, 0.f, 0.f, 0.f};
                    #pragma unroll
                    for (int kt = 0; kt < 3; ++kt)
                        a = __builtin_amdgcn_mfma_f32_16x16x32_f16(
                                __builtin_bit_cast(half8, afr[s][kt]),
                                __builtin_bit_cast(half8, bfr[kt]), a, 0, 0, 0);
                    acc[s] = a;
                }
            }
            // y_{it-1} = w_out . h_{it-1}: D[0][*] of tile 24 (quad 0, reg x)
            if (wave == 5 && lane == 0 && it > 0)
                y_buf[((it - 1) >> 7) & 1][(it - 1) & (CHUNK - 1)] = acc[4].x + bout;
        }

        // ring flush: chunk [it-1-CHUNK, it-1) complete; wave 4, lanes 0..31
        if ((it & (CHUNK - 1)) == 1 && it > 1 && wave == 4 && lane < 32) {
            const int base = it - 1 - CHUNK;
            const int pb = (base >> 7) & 1;
            const f32x4 v = *reinterpret_cast<const f32x4*>(&y_buf[pb][lane * 4]);
            *reinterpret_cast<f32x4*>(&yrow[base + lane * 4]) = v;
        }

        if (it < T_LEN) {
            // in-lane: pick the owned tile's gates (acc cols identical)
            const int sel = m & 3;
            f32x4 g4 = acc[0];
            if (sel == 1) g4 = acc[1];
            if (sel == 2) g4 = acc[2];
            if (sel == 3) g4 = acc[3];
            const float s0 = g4.x + bias4[0] + x_cur * wih4[0];
            const float s1 = g4.y + bias4[1] + x_cur * wih4[1];
            const float s2 = g4.z + bias4[2] + x_cur * wih4[2];
            const float s3 = g4.w + bias4[3] + x_cur * wih4[3];
            const float ig = fast_sigmoid(s0);
            const float fg = fast_sigmoid(s1);
            const float gg = fast_tanh(s2);
            const float og = fast_sigmoid(s3);
            c = fg * c + ig * gg;
            const float h = og * fast_tanh(c);
            if (m < 4) h_s[p ^ 1][cell] = (_Float16)h;  // 16 lanes/wave, 2-way max
        }
        __syncthreads();  // h_s[p^1] + y_buf ready
    }
}

extern "C" void kernel_launch(void* const* d_in, const int* in_sizes, int n_in,
                              void* d_out, int out_size, void* d_ws, size_t ws_size,
                              hipStream_t stream) {
    const float* x     = (const float*)d_in[0];
    const float* w_ih  = (const float*)d_in[1];
    const float* w_hh  = (const float*)d_in[2];
    const float* b_ih  = (const float*)d_in[3];
    const float* b_hh  = (const float*)d_in[4];
    const float* w_out = (const float*)d_in[5];
    const float* b_out = (const float*)d_in[6];
    float* y = (float*)d_out;

    const int B = 128;
    lstm_mfma2_kernel<<<dim3(B), dim3(NTHR), 0, stream>>>(
        x, w_ih, w_hh, b_ih, b_hh, w_out, b_out, y);
}

// Round 6
// 5023.276 us; speedup vs baseline: 1.2108x; 1.2108x over previous
//
#include <hip/hip_runtime.h>

// SimpleLSTM B=128,T=8192,H=96. One block per batch, 384 threads (6 waves).
// R5 post-mortem: AMDGPUPromoteAlloca demoted per-thread arrays (acc[5]) to
// LDS (LDS_Block_Size 32 KB, 2.5e7 bank conflicts, VGPR only 56). R6: every
// per-thread array is now a NAMED SCALAR (no alloca => nothing to demote);
// x is staged in LDS once so the steady-state loop has zero global loads
// (the vmcnt(0) drain before each s_barrier never waits on VMEM).
// Structure (1 barrier/step, in-lane cell update):
//   - W_hh rows PERMUTED: tile mt row m <-> orig row (m&3)*96 + 4mt + (m>>2)
//     => D reg r of lane (mt,quad) = gate r (i,f,g,o) of cell 4mt+quad;
//     all 16 D cols identical (B cols all carry the same h).
//   - wave w owns tiles 4w..4w+3; lane updates cell 16w+4*(m&3)+quad
//     (4x redundant across m>>2); m<4 lanes write h (fp16, double-buffered).
//   - wave 5 owns a 25th tile whose row 0 = w_out => y_t from MFMA; y staged
//     in an LDS ring, flushed 128-at-a-time by wave 4.
// fp16 only on W_hh/w_out/h (MFMA inputs); x, biases, gates, c, y in fp32.

#define T_LEN 8192
#define H_DIM 96
#define NTHR  384   // 6 waves
#define CHUNK 128   // y-ring flush granularity

typedef float    f32x4 __attribute__((ext_vector_type(4)));
typedef _Float16 half8 __attribute__((ext_vector_type(8)));

#define MFMA16(A, B, C)                                                        \
    __builtin_amdgcn_mfma_f32_16x16x32_f16(__builtin_bit_cast(half8, (A)),     \
                                           __builtin_bit_cast(half8, (B)),     \
                                           (C), 0, 0, 0)

__device__ __forceinline__ float fast_sigmoid(float v) {
    return 1.0f / (1.0f + __expf(-v));
}
__device__ __forceinline__ float fast_tanh(float v) {
    return 1.0f - 2.0f / (__expf(2.0f * v) + 1.0f);  // stable at +-inf
}

__device__ __forceinline__ f32x4 load_afrag(const float* __restrict__ w_hh,
                                            const float* __restrict__ w_out,
                                            int mt, int kt, int m, int quad) {
    half8 f;
    if (mt < 24) {
        const int orig = (m & 3) * 96 + 4 * mt + (m >> 2);
        const float* src = w_hh + orig * H_DIM + kt * 32 + quad * 8;
        #pragma unroll
        for (int jj = 0; jj < 8; ++jj) f[jj] = (_Float16)src[jj];
    } else {  // y tile: row 0 = w_out, rows 1..15 = 0
        #pragma unroll
        for (int jj = 0; jj < 8; ++jj)
            f[jj] = (m == 0) ? (_Float16)w_out[kt * 32 + quad * 8 + jj]
                             : (_Float16)0.0f;
    }
    return __builtin_bit_cast(f32x4, f);
}

__global__ __launch_bounds__(NTHR, 1) void lstm_mfma3_kernel(
    const float* __restrict__ x,      // [B, T]
    const float* __restrict__ w_ih,   // [4H]
    const float* __restrict__ w_hh,   // [4H, H]
    const float* __restrict__ b_ih,   // [4H]
    const float* __restrict__ b_hh,   // [4H]
    const float* __restrict__ w_out,  // [H]
    const float* __restrict__ b_out,  // [1]
    float* __restrict__ y)            // [B, T]
{
    const int b    = blockIdx.x;
    const int tid  = threadIdx.x;
    const int wave = tid >> 6;
    const int lane = tid & 63;
    const int m    = lane & 15;
    const int quad = lane >> 4;

    __shared__ __align__(16) _Float16 h_s[2][H_DIM];
    __shared__ __align__(16) float    y_buf[2][CHUNK];
    __shared__ __align__(16) float    x_s[T_LEN];      // whole input row, 32 KB

    const float* xrow = x + (size_t)b * T_LEN;
    float*       yrow = y + (size_t)b * T_LEN;

    // ---- stage x into LDS (one-time; 16B-aligned vec4 loads)
    for (int i = tid * 4; i < T_LEN; i += NTHR * 4)
        *reinterpret_cast<f32x4*>(&x_s[i]) =
            *reinterpret_cast<const f32x4*>(&xrow[i]);

    // ---- A fragments: 15 NAMED f32x4 (no alloca!). Wave w tiles 4w..4w+3,
    //      wave 5 additionally tile 24 (y). Pinned via asm value barrier.
    const int mt0 = 4 * wave;
    f32x4 af00 = load_afrag(w_hh, w_out, mt0 + 0, 0, m, quad);
    f32x4 af01 = load_afrag(w_hh, w_out, mt0 + 0, 1, m, quad);
    f32x4 af02 = load_afrag(w_hh, w_out, mt0 + 0, 2, m, quad);
    f32x4 af10 = load_afrag(w_hh, w_out, mt0 + 1, 0, m, quad);
    f32x4 af11 = load_afrag(w_hh, w_out, mt0 + 1, 1, m, quad);
    f32x4 af12 = load_afrag(w_hh, w_out, mt0 + 1, 2, m, quad);
    f32x4 af20 = load_afrag(w_hh, w_out, mt0 + 2, 0, m, quad);
    f32x4 af21 = load_afrag(w_hh, w_out, mt0 + 2, 1, m, quad);
    f32x4 af22 = load_afrag(w_hh, w_out, mt0 + 2, 2, m, quad);
    f32x4 af30 = load_afrag(w_hh, w_out, mt0 + 3, 0, m, quad);
    f32x4 af31 = load_afrag(w_hh, w_out, mt0 + 3, 1, m, quad);
    f32x4 af32 = load_afrag(w_hh, w_out, mt0 + 3, 2, m, quad);
    f32x4 afy0 = {0.f, 0.f, 0.f, 0.f};
    f32x4 afy1 = {0.f, 0.f, 0.f, 0.f};
    f32x4 afy2 = {0.f, 0.f, 0.f, 0.f};
    if (wave == 5) {
        afy0 = load_afrag(w_hh, w_out, 24, 0, m, quad);
        afy1 = load_afrag(w_hh, w_out, 24, 1, m, quad);
        afy2 = load_afrag(w_hh, w_out, 24, 2, m, quad);
    }
    asm volatile("" : "+v"(af00), "+v"(af01), "+v"(af02), "+v"(af10),
                      "+v"(af11), "+v"(af12), "+v"(af20), "+v"(af21));
    asm volatile("" : "+v"(af22), "+v"(af30), "+v"(af31), "+v"(af32),
                      "+v"(afy0), "+v"(afy1), "+v"(afy2));

    // ---- per-lane cell params (named scalars): cell = 16w + 4*(m&3) + quad
    const int cell = 16 * wave + 4 * (m & 3) + quad;
    const float bias_i = b_ih[0 * H_DIM + cell] + b_hh[0 * H_DIM + cell];
    const float bias_f = b_ih[1 * H_DIM + cell] + b_hh[1 * H_DIM + cell];
    const float bias_g = b_ih[2 * H_DIM + cell] + b_hh[2 * H_DIM + cell];
    const float bias_o = b_ih[3 * H_DIM + cell] + b_hh[3 * H_DIM + cell];
    const float wih_i  = w_ih[0 * H_DIM + cell];
    const float wih_f  = w_ih[1 * H_DIM + cell];
    const float wih_g  = w_ih[2 * H_DIM + cell];
    const float wih_o  = w_ih[3 * H_DIM + cell];
    const float bout   = b_out[0];
    float c = 0.f;
    if (tid < H_DIM) h_s[0][tid] = (_Float16)0.0f;
    __syncthreads();

    // iter it: reads h_{it-1} (h_s[it&1]); makes h_it; y tile -> y_{it-1}.
    // it==T_LEN: y_{T-1} into ring only; it==T_LEN+1: final ring flush only.
    for (int it = 0; it <= T_LEN + 1; ++it) {
        const int p = it & 1;

        f32x4 acc0 = {0.f, 0.f, 0.f, 0.f};
        f32x4 acc1 = {0.f, 0.f, 0.f, 0.f};
        f32x4 acc2 = {0.f, 0.f, 0.f, 0.f};
        f32x4 acc3 = {0.f, 0.f, 0.f, 0.f};
        f32x4 accy = {0.f, 0.f, 0.f, 0.f};

        float x_cur = 0.f;
        if (it < T_LEN) x_cur = x_s[it];  // LDS broadcast read

        if (it <= T_LEN) {
            const f32x4 b0 = *reinterpret_cast<const f32x4*>(&h_s[p][quad * 8]);
            const f32x4 b1 = *reinterpret_cast<const f32x4*>(&h_s[p][32 + quad * 8]);
            const f32x4 b2 = *reinterpret_cast<const f32x4*>(&h_s[p][64 + quad * 8]);
            acc0 = MFMA16(af00, b0, acc0);
            acc0 = MFMA16(af01, b1, acc0);
            acc0 = MFMA16(af02, b2, acc0);
            acc1 = MFMA16(af10, b0, acc1);
            acc1 = MFMA16(af11, b1, acc1);
            acc1 = MFMA16(af12, b2, acc1);
            acc2 = MFMA16(af20, b0, acc2);
            acc2 = MFMA16(af21, b1, acc2);
            acc2 = MFMA16(af22, b2, acc2);
            acc3 = MFMA16(af30, b0, acc3);
            acc3 = MFMA16(af31, b1, acc3);
            acc3 = MFMA16(af32, b2, acc3);
            if (wave == 5) {
                accy = MFMA16(afy0, b0, accy);
                accy = MFMA16(afy1, b1, accy);
                accy = MFMA16(afy2, b2, accy);
                if (lane == 0 && it > 0)
                    y_buf[((it - 1) >> 7) & 1][(it - 1) & (CHUNK - 1)] =
                        accy.x + bout;
            }
        }

        // ring flush: chunk [it-1-CHUNK, it-1) is complete; wave 4 lanes 0..31
        if ((it & (CHUNK - 1)) == 1 && it > 1 && wave == 4 && lane < 32) {
            const int base = it - 1 - CHUNK;
            const int pb = (base >> 7) & 1;
            const f32x4 v =
                *reinterpret_cast<const f32x4*>(&y_buf[pb][lane * 4]);
            *reinterpret_cast<f32x4*>(&yrow[base + lane * 4]) = v;
        }

        if (it < T_LEN) {
            // in-lane gate pick (acc cols identical); per-lane sel = m&3
            const int sel = m & 3;
            const f32x4 g4 = (sel == 0) ? acc0
                           : (sel == 1) ? acc1
                           : (sel == 2) ? acc2 : acc3;
            const float s0 = g4.x + bias_i + x_cur * wih_i;
            const float s1 = g4.y + bias_f + x_cur * wih_f;
            const float s2 = g4.z + bias_g + x_cur * wih_g;
            const float s3 = g4.w + bias_o + x_cur * wih_o;
            const float ig = fast_sigmoid(s0);
            const float fg = fast_sigmoid(s1);
            const float gg = fast_tanh(s2);
            const float og = fast_sigmoid(s3);
            c = fg * c + ig * gg;
            const float h = og * fast_tanh(c);
            if (m < 4) h_s[p ^ 1][cell] = (_Float16)h;  // 16 lanes/wave
        }
        __syncthreads();  // h_s[p^1] + y_buf ready
    }
}

extern "C" void kernel_launch(void* const* d_in, const int* in_sizes, int n_in,
                              void* d_out, int out_size, void* d_ws, size_t ws_size,
                              hipStream_t stream) {
    const float* x     = (const float*)d_in[0];
    const float* w_ih  = (const float*)d_in[1];
    const float* w_hh  = (const float*)d_in[2];
    const float* b_ih  = (const float*)d_in[3];
    const float* b_hh  = (const float*)d_in[4];
    const float* w_out = (const float*)d_in[5];
    const float* b_out = (const float*)d_in[6];
    float* y = (float*)d_out;

    const int B = 128;
    lstm_mfma3_kernel<<<dim3(B), dim3(NTHR), 0, stream>>>(
        x, w_ih, w_hh, b_ih, b_hh, w_out, b_out, y);
}

// Round 7
// 4812.584 us; speedup vs baseline: 1.2638x; 1.0438x over previous
//
#include <hip/hip_runtime.h>

// SimpleLSTM B=128,T=8192,H=96. One block per batch, 256 threads (4 waves).
// R6 post-mortem: step ~1470 cyc, issue-bound: 6 waves redundantly issuing
// the activation chain (~350 cyc VALU issue) + 26 DS instrs serializing on
// the LDS pipe after each barrier + 6-wave barrier skew. R7: 4 waves --
// same total MFMA (75 instrs/step, 1 wave/SIMD), but VALU issue per SIMD
// halves, DS reads drop 18->12 b128, barrier syncs 4 waves not 6.
//   - W_hh rows PERMUTED: tile mt row m <-> orig row (m&3)*96 + 4mt + (m>>2)
//     => D reg r of lane (*,quad) of tile mt = gate r (i,f,g,o) of cell
//     4mt+quad; all 16 D cols identical (B cols all carry the same h).
//   - wave w owns tiles 6w..6w+5; lane (m,quad) updates cell 24w+4*(m%6)+quad
//     (redundant across m; m<6 lanes write h, fp16, double-buffered).
//   - wave 3 owns the 25th tile (row 0 = w_out) => y_t from MFMA; y staged in
//     an LDS ring, flushed 128-at-a-time by wave 0.
//   - x staged in LDS once: steady-state loop has zero global loads (the
//     vmcnt(0) drain before s_barrier never waits on VMEM).
// All per-thread state is NAMED SCALARS (R5 lesson: arrays -> PromoteAlloca
// -> LDS catastrophe). fp16 only on W_hh/w_out/h; everything else fp32.

#define T_LEN 8192
#define H_DIM 96
#define NTHR  256   // 4 waves
#define CHUNK 128   // y-ring flush granularity

typedef float    f32x4 __attribute__((ext_vector_type(4)));
typedef _Float16 half8 __attribute__((ext_vector_type(8)));

#define MFMA16(A, B, C)                                                        \
    __builtin_amdgcn_mfma_f32_16x16x32_f16(__builtin_bit_cast(half8, (A)),     \
                                           __builtin_bit_cast(half8, (B)),     \
                                           (C), 0, 0, 0)

__device__ __forceinline__ float fast_sigmoid(float v) {
    return 1.0f / (1.0f + __expf(-v));
}
__device__ __forceinline__ float fast_tanh(float v) {
    return 1.0f - 2.0f / (__expf(2.0f * v) + 1.0f);  // stable at +-inf
}

__device__ __forceinline__ f32x4 load_afrag(const float* __restrict__ w_hh,
                                            const float* __restrict__ w_out,
                                            int mt, int kt, int m, int quad) {
    half8 f;
    if (mt < 24) {
        const int orig = (m & 3) * 96 + 4 * mt + (m >> 2);
        const float* src = w_hh + orig * H_DIM + kt * 32 + quad * 8;
        #pragma unroll
        for (int jj = 0; jj < 8; ++jj) f[jj] = (_Float16)src[jj];
    } else {  // y tile: row 0 = w_out, rows 1..15 = 0
        #pragma unroll
        for (int jj = 0; jj < 8; ++jj)
            f[jj] = (m == 0) ? (_Float16)w_out[kt * 32 + quad * 8 + jj]
                             : (_Float16)0.0f;
    }
    return __builtin_bit_cast(f32x4, f);
}

__global__ __launch_bounds__(NTHR, 1) void lstm_mfma4_kernel(
    const float* __restrict__ x,      // [B, T]
    const float* __restrict__ w_ih,   // [4H]
    const float* __restrict__ w_hh,   // [4H, H]
    const float* __restrict__ b_ih,   // [4H]
    const float* __restrict__ b_hh,   // [4H]
    const float* __restrict__ w_out,  // [H]
    const float* __restrict__ b_out,  // [1]
    float* __restrict__ y)            // [B, T]
{
    const int b    = blockIdx.x;
    const int tid  = threadIdx.x;
    const int wave = tid >> 6;
    const int lane = tid & 63;
    const int m    = lane & 15;
    const int quad = lane >> 4;

    __shared__ __align__(16) _Float16 h_s[2][H_DIM];
    __shared__ __align__(16) float    y_buf[2][CHUNK];
    __shared__ __align__(16) float    x_s[T_LEN];      // whole input row, 32 KB

    const float* xrow = x + (size_t)b * T_LEN;
    float*       yrow = y + (size_t)b * T_LEN;

    // ---- stage x into LDS (one-time; 16B-aligned vec4 loads)
    for (int i = tid * 4; i < T_LEN; i += NTHR * 4)
        *reinterpret_cast<f32x4*>(&x_s[i]) =
            *reinterpret_cast<const f32x4*>(&xrow[i]);

    // ---- A fragments: wave w tiles 6w..6w+5 (18 named f32x4), wave 3 also
    //      tile 24 (y). Pinned via asm value barrier (R2-R6 lesson).
    const int mt0 = 6 * wave;
    f32x4 af00 = load_afrag(w_hh, w_out, mt0 + 0, 0, m, quad);
    f32x4 af01 = load_afrag(w_hh, w_out, mt0 + 0, 1, m, quad);
    f32x4 af02 = load_afrag(w_hh, w_out, mt0 + 0, 2, m, quad);
    f32x4 af10 = load_afrag(w_hh, w_out, mt0 + 1, 0, m, quad);
    f32x4 af11 = load_afrag(w_hh, w_out, mt0 + 1, 1, m, quad);
    f32x4 af12 = load_afrag(w_hh, w_out, mt0 + 1, 2, m, quad);
    f32x4 af20 = load_afrag(w_hh, w_out, mt0 + 2, 0, m, quad);
    f32x4 af21 = load_afrag(w_hh, w_out, mt0 + 2, 1, m, quad);
    f32x4 af22 = load_afrag(w_hh, w_out, mt0 + 2, 2, m, quad);
    f32x4 af30 = load_afrag(w_hh, w_out, mt0 + 3, 0, m, quad);
    f32x4 af31 = load_afrag(w_hh, w_out, mt0 + 3, 1, m, quad);
    f32x4 af32 = load_afrag(w_hh, w_out, mt0 + 3, 2, m, quad);
    f32x4 af40 = load_afrag(w_hh, w_out, mt0 + 4, 0, m, quad);
    f32x4 af41 = load_afrag(w_hh, w_out, mt0 + 4, 1, m, quad);
    f32x4 af42 = load_afrag(w_hh, w_out, mt0 + 4, 2, m, quad);
    f32x4 af50 = load_afrag(w_hh, w_out, mt0 + 5, 0, m, quad);
    f32x4 af51 = load_afrag(w_hh, w_out, mt0 + 5, 1, m, quad);
    f32x4 af52 = load_afrag(w_hh, w_out, mt0 + 5, 2, m, quad);
    f32x4 afy0 = {0.f, 0.f, 0.f, 0.f};
    f32x4 afy1 = {0.f, 0.f, 0.f, 0.f};
    f32x4 afy2 = {0.f, 0.f, 0.f, 0.f};
    if (wave == 3) {
        afy0 = load_afrag(w_hh, w_out, 24, 0, m, quad);
        afy1 = load_afrag(w_hh, w_out, 24, 1, m, quad);
        afy2 = load_afrag(w_hh, w_out, 24, 2, m, quad);
    }
    asm volatile("" : "+v"(af00), "+v"(af01), "+v"(af02), "+v"(af10),
                      "+v"(af11), "+v"(af12), "+v"(af20));
    asm volatile("" : "+v"(af21), "+v"(af22), "+v"(af30), "+v"(af31),
                      "+v"(af32), "+v"(af40), "+v"(af41));
    asm volatile("" : "+v"(af42), "+v"(af50), "+v"(af51), "+v"(af52),
                      "+v"(afy0), "+v"(afy1), "+v"(afy2));

    // ---- per-lane cell params: sel = m % 6, cell = 24w + 4*sel + quad
    const int sel  = (m >= 12) ? (m - 12) : ((m >= 6) ? (m - 6) : m);
    const int cell = 24 * wave + 4 * sel + quad;
    const float bias_i = b_ih[0 * H_DIM + cell] + b_hh[0 * H_DIM + cell];
    const float bias_f = b_ih[1 * H_DIM + cell] + b_hh[1 * H_DIM + cell];
    const float bias_g = b_ih[2 * H_DIM + cell] + b_hh[2 * H_DIM + cell];
    const float bias_o = b_ih[3 * H_DIM + cell] + b_hh[3 * H_DIM + cell];
    const float wih_i  = w_ih[0 * H_DIM + cell];
    const float wih_f  = w_ih[1 * H_DIM + cell];
    const float wih_g  = w_ih[2 * H_DIM + cell];
    const float wih_o  = w_ih[3 * H_DIM + cell];
    const float bout   = b_out[0];
    float c = 0.f;
    if (tid < H_DIM) h_s[0][tid] = (_Float16)0.0f;
    __syncthreads();

    // iter it: reads h_{it-1} (h_s[it&1]); makes h_it; y tile -> y_{it-1}.
    // it==T_LEN: y_{T-1} into ring only; it==T_LEN+1: final ring flush only.
    for (int it = 0; it <= T_LEN + 1; ++it) {
        const int p = it & 1;

        f32x4 acc0 = {0.f, 0.f, 0.f, 0.f};
        f32x4 acc1 = {0.f, 0.f, 0.f, 0.f};
        f32x4 acc2 = {0.f, 0.f, 0.f, 0.f};
        f32x4 acc3 = {0.f, 0.f, 0.f, 0.f};
        f32x4 acc4 = {0.f, 0.f, 0.f, 0.f};
        f32x4 acc5 = {0.f, 0.f, 0.f, 0.f};
        f32x4 accy = {0.f, 0.f, 0.f, 0.f};

        float x_cur = 0.f;
        if (it < T_LEN) x_cur = x_s[it];  // uniform LDS broadcast

        if (it <= T_LEN) {
            const f32x4 b0 = *reinterpret_cast<const f32x4*>(&h_s[p][quad * 8]);
            const f32x4 b1 = *reinterpret_cast<const f32x4*>(&h_s[p][32 + quad * 8]);
            const f32x4 b2 = *reinterpret_cast<const f32x4*>(&h_s[p][64 + quad * 8]);
            acc0 = MFMA16(af00, b0, acc0);
            acc0 = MFMA16(af01, b1, acc0);
            acc0 = MFMA16(af02, b2, acc0);
            acc1 = MFMA16(af10, b0, acc1);
            acc1 = MFMA16(af11, b1, acc1);
            acc1 = MFMA16(af12, b2, acc1);
            acc2 = MFMA16(af20, b0, acc2);
            acc2 = MFMA16(af21, b1, acc2);
            acc2 = MFMA16(af22, b2, acc2);
            acc3 = MFMA16(af30, b0, acc3);
            acc3 = MFMA16(af31, b1, acc3);
            acc3 = MFMA16(af32, b2, acc3);
            acc4 = MFMA16(af40, b0, acc4);
            acc4 = MFMA16(af41, b1, acc4);
            acc4 = MFMA16(af42, b2, acc4);
            acc5 = MFMA16(af50, b0, acc5);
            acc5 = MFMA16(af51, b1, acc5);
            acc5 = MFMA16(af52, b2, acc5);
            if (wave == 3) {
                accy = MFMA16(afy0, b0, accy);
                accy = MFMA16(afy1, b1, accy);
                accy = MFMA16(afy2, b2, accy);
                if (lane == 0 && it > 0)
                    y_buf[((it - 1) >> 7) & 1][(it - 1) & (CHUNK - 1)] =
                        accy.x + bout;
            }
        }

        // ring flush: chunk [it-1-CHUNK, it-1) complete; wave 0, lanes 0..31
        if ((it & (CHUNK - 1)) == 1 && it > 1 && wave == 0 && lane < 32) {
            const int base = it - 1 - CHUNK;
            const int pb = (base >> 7) & 1;
            const f32x4 v =
                *reinterpret_cast<const f32x4*>(&y_buf[pb][lane * 4]);
            *reinterpret_cast<f32x4*>(&yrow[base + lane * 4]) = v;
        }

        if (it < T_LEN) {
            // in-lane gate pick (all D cols identical): 5-deep cndmask chain
            f32x4 g4 = acc0;
            if (sel == 1) g4 = acc1;
            if (sel == 2) g4 = acc2;
            if (sel == 3) g4 = acc3;
            if (sel == 4) g4 = acc4;
            if (sel == 5) g4 = acc5;
            const float s0 = g4.x + bias_i + x_cur * wih_i;
            const float s1 = g4.y + bias_f + x_cur * wih_f;
            const float s2 = g4.z + bias_g + x_cur * wih_g;
            const float s3 = g4.w + bias_o + x_cur * wih_o;
            const float ig = fast_sigmoid(s0);
            const float fg = fast_sigmoid(s1);
            const float gg = fast_tanh(s2);
            const float og = fast_sigmoid(s3);
            c = fg * c + ig * gg;
            const float h = og * fast_tanh(c);
            if (m < 6) h_s[p ^ 1][cell] = (_Float16)h;  // 24 lanes/wave, unique cells
        }
        __syncthreads();  // h_s[p^1] + y_buf ready
    }
}

extern "C" void kernel_launch(void* const* d_in, const int* in_sizes, int n_in,
                              void* d_out, int out_size, void* d_ws, size_t ws_size,
                              hipStream_t stream) {
    const float* x     = (const float*)d_in[0];
    const float* w_ih  = (const float*)d_in[1];
    const float* w_hh  = (const float*)d_in[2];
    const float* b_ih  = (const float*)d_in[3];
    const float* b_hh  = (const float*)d_in[4];
    const float* w_out = (const float*)d_in[5];
    const float* b_out = (const float*)d_in[6];
    float* y = (float*)d_out;

    const int B = 128;
    lstm_mfma4_kernel<<<dim3(B), dim3(NTHR), 0, stream>>>(
        x, w_ih, w_hh, b_ih, b_hh, w_out, b_out, y);
}

// Round 9
// 4707.807 us; speedup vs baseline: 1.2919x; 1.0223x over previous
//
#include <hip/hip_runtime.h>

// SimpleLSTM B=128,T=8192,H=96. R8 post-mortem: NaN from an init bug --
// h0 zero-init used `lane < 96` but a wave has 64 lanes, so h cells 64..95
// were never zeroed. Fixed: each group's 256 threads cover all 96 cells.
// Structure (unchanged intent from R8): 64 blocks x 512 threads; waves 0-3 =
// batch 2b, waves 4-7 = batch 2b+1 -> 2 INDEPENDENT waves per SIMD so one
// wave's MFMA/DS/exp stalls are filled by the other. VALU trims: pinned zero
// C-operand (no per-step acc-init movs), exp2-domain prescale (w_hh/w_ih/
// biases x log2e, g-rows x 2log2e) so activations are exp2+add+rcp.
// Per-group structure = R7: permuted W rows => D reg r of lane (m,quad),
// tile mt = gate r of cell 4mt+quad; all 16 D cols identical; wave wv owns
// tiles 6wv..6wv+5; lane updates cell 24wv+4*(m%6)+quad; wv3 owns y-tile
// (row0=w_out unscaled); y via LDS ring flushed by wv0; x fully in LDS.
// All per-thread state NAMED SCALARS (R5 PromoteAlloca lesson).

#define T_LEN 8192
#define H_DIM 96
#define NTHR  512   // 8 waves: 2 groups x 4
#define CHUNK 128
#define LOG2E 1.44269504f

typedef float    f32x4 __attribute__((ext_vector_type(4)));
typedef _Float16 half8 __attribute__((ext_vector_type(8)));

#define MFMA16(A, B, C)                                                        \
    __builtin_amdgcn_mfma_f32_16x16x32_f16(__builtin_bit_cast(half8, (A)),     \
                                           __builtin_bit_cast(half8, (B)),     \
                                           (C), 0, 0, 0)

// exp2-domain activations (inputs pre-scaled by log2e / 2log2e)
__device__ __forceinline__ float sig2(float s) {   // sigmoid, s = log2e*pre
    return __builtin_amdgcn_rcpf(1.0f + __builtin_amdgcn_exp2f(-s));
}
__device__ __forceinline__ float tanh2(float sg) { // tanh, sg = 2log2e*pre
    return 1.0f - 2.0f * __builtin_amdgcn_rcpf(1.0f + __builtin_amdgcn_exp2f(sg));
}

__device__ __forceinline__ f32x4 load_afrag(const float* __restrict__ w_hh,
                                            const float* __restrict__ w_out,
                                            int mt, int kt, int m, int quad) {
    half8 f;
    if (mt < 24) {
        const int r = m & 3;                       // gate: 0=i 1=f 2=g 3=o
        const float scale = (r == 2) ? 2.0f * LOG2E : LOG2E;
        const int orig = r * 96 + 4 * mt + (m >> 2);
        const float* src = w_hh + orig * H_DIM + kt * 32 + quad * 8;
        #pragma unroll
        for (int jj = 0; jj < 8; ++jj) f[jj] = (_Float16)(scale * src[jj]);
    } else {  // y tile: row 0 = w_out (unscaled), rows 1..15 = 0
        #pragma unroll
        for (int jj = 0; jj < 8; ++jj)
            f[jj] = (m == 0) ? (_Float16)w_out[kt * 32 + quad * 8 + jj]
                             : (_Float16)0.0f;
    }
    return __builtin_bit_cast(f32x4, f);
}

__global__ __launch_bounds__(NTHR, 2) void lstm_mfma6_kernel(
    const float* __restrict__ x,      // [B, T]
    const float* __restrict__ w_ih,   // [4H]
    const float* __restrict__ w_hh,   // [4H, H]
    const float* __restrict__ b_ih,   // [4H]
    const float* __restrict__ b_hh,   // [4H]
    const float* __restrict__ w_out,  // [H]
    const float* __restrict__ b_out,  // [1]
    float* __restrict__ y)            // [B, T]
{
    const int tid  = threadIdx.x;
    const int wave = tid >> 6;
    const int grp  = wave >> 2;       // 0/1: which batch of the pair
    const int wv   = wave & 3;        // role within group (R7's "wave")
    const int lane = tid & 63;
    const int m    = lane & 15;
    const int quad = lane >> 4;
    const int bat  = 2 * blockIdx.x + grp;

    __shared__ __align__(16) _Float16 h_s[2][2][H_DIM];   // [grp][buf][cell]
    __shared__ __align__(16) float    y_buf[2][2][CHUNK]; // [grp][ring][i]
    __shared__ __align__(16) float    x_s[2][T_LEN];      // 64 KB

    const float* xrow = x + (size_t)bat * T_LEN;
    float*       yrow = y + (size_t)bat * T_LEN;

    // ---- stage this group's x into LDS (256 threads per group)
    for (int i = (tid & 255) * 4; i < T_LEN; i += 1024)
        *reinterpret_cast<f32x4*>(&x_s[grp][i]) =
            *reinterpret_cast<const f32x4*>(&xrow[i]);

    // ---- A fragments (named, pinned). wv owns tiles 6wv..6wv+5; wv3: +y tile
    const int mt0 = 6 * wv;
    f32x4 af00 = load_afrag(w_hh, w_out, mt0 + 0, 0, m, quad);
    f32x4 af01 = load_afrag(w_hh, w_out, mt0 + 0, 1, m, quad);
    f32x4 af02 = load_afrag(w_hh, w_out, mt0 + 0, 2, m, quad);
    f32x4 af10 = load_afrag(w_hh, w_out, mt0 + 1, 0, m, quad);
    f32x4 af11 = load_afrag(w_hh, w_out, mt0 + 1, 1, m, quad);
    f32x4 af12 = load_afrag(w_hh, w_out, mt0 + 1, 2, m, quad);
    f32x4 af20 = load_afrag(w_hh, w_out, mt0 + 2, 0, m, quad);
    f32x4 af21 = load_afrag(w_hh, w_out, mt0 + 2, 1, m, quad);
    f32x4 af22 = load_afrag(w_hh, w_out, mt0 + 2, 2, m, quad);
    f32x4 af30 = load_afrag(w_hh, w_out, mt0 + 3, 0, m, quad);
    f32x4 af31 = load_afrag(w_hh, w_out, mt0 + 3, 1, m, quad);
    f32x4 af32 = load_afrag(w_hh, w_out, mt0 + 3, 2, m, quad);
    f32x4 af40 = load_afrag(w_hh, w_out, mt0 + 4, 0, m, quad);
    f32x4 af41 = load_afrag(w_hh, w_out, mt0 + 4, 1, m, quad);
    f32x4 af42 = load_afrag(w_hh, w_out, mt0 + 4, 2, m, quad);
    f32x4 af50 = load_afrag(w_hh, w_out, mt0 + 5, 0, m, quad);
    f32x4 af51 = load_afrag(w_hh, w_out, mt0 + 5, 1, m, quad);
    f32x4 af52 = load_afrag(w_hh, w_out, mt0 + 5, 2, m, quad);
    f32x4 afy0 = {0.f, 0.f, 0.f, 0.f};
    f32x4 afy1 = {0.f, 0.f, 0.f, 0.f};
    f32x4 afy2 = {0.f, 0.f, 0.f, 0.f};
    if (wv == 3) {
        afy0 = load_afrag(w_hh, w_out, 24, 0, m, quad);
        afy1 = load_afrag(w_hh, w_out, 24, 1, m, quad);
        afy2 = load_afrag(w_hh, w_out, 24, 2, m, quad);
    }
    f32x4 zero4 = {0.f, 0.f, 0.f, 0.f};
    asm volatile("" : "+v"(af00), "+v"(af01), "+v"(af02), "+v"(af10),
                      "+v"(af11), "+v"(af12), "+v"(af20));
    asm volatile("" : "+v"(af21), "+v"(af22), "+v"(af30), "+v"(af31),
                      "+v"(af32), "+v"(af40), "+v"(af41));
    asm volatile("" : "+v"(af42), "+v"(af50), "+v"(af51), "+v"(af52),
                      "+v"(afy0), "+v"(afy1), "+v"(afy2), "+v"(zero4));

    // ---- per-lane cell params (exp2-domain prescaled)
    const int sel  = (m >= 12) ? (m - 12) : ((m >= 6) ? (m - 6) : m);
    const int cell = 24 * wv + 4 * sel + quad;
    const float bias_i = LOG2E * (b_ih[0 * H_DIM + cell] + b_hh[0 * H_DIM + cell]);
    const float bias_f = LOG2E * (b_ih[1 * H_DIM + cell] + b_hh[1 * H_DIM + cell]);
    const float bias_g = 2.0f * LOG2E * (b_ih[2 * H_DIM + cell] + b_hh[2 * H_DIM + cell]);
    const float bias_o = LOG2E * (b_ih[3 * H_DIM + cell] + b_hh[3 * H_DIM + cell]);
    const float wih_i  = LOG2E * w_ih[0 * H_DIM + cell];
    const float wih_f  = LOG2E * w_ih[1 * H_DIM + cell];
    const float wih_g  = 2.0f * LOG2E * w_ih[2 * H_DIM + cell];
    const float wih_o  = LOG2E * w_ih[3 * H_DIM + cell];
    const float bout   = b_out[0];
    float c = 0.f;
    // FIX (R8 bug): cover ALL 96 cells per group -- 256 threads/group, first
    // 96 of each group's tid&255 write one cell each. (A wave has 64 lanes;
    // the old `lane < 96` left cells 64..95 uninitialized -> NaN.)
    if ((tid & 255) < H_DIM) h_s[grp][0][tid & 255] = (_Float16)0.0f;
    __syncthreads();

    // iter it: reads h_{it-1} (h_s[grp][it&1]); makes h_it; y tile->y_{it-1}
    for (int it = 0; it <= T_LEN + 1; ++it) {
        const int p = it & 1;

        f32x4 acc0, acc1, acc2, acc3, acc4, acc5, accy;
        float x_cur = 0.f;
        if (it < T_LEN) x_cur = x_s[grp][it];  // uniform LDS broadcast

        if (it <= T_LEN) {
            const f32x4 b0 = *reinterpret_cast<const f32x4*>(&h_s[grp][p][quad * 8]);
            const f32x4 b1 = *reinterpret_cast<const f32x4*>(&h_s[grp][p][32 + quad * 8]);
            const f32x4 b2 = *reinterpret_cast<const f32x4*>(&h_s[grp][p][64 + quad * 8]);
            acc0 = MFMA16(af00, b0, zero4);
            acc0 = MFMA16(af01, b1, acc0);
            acc0 = MFMA16(af02, b2, acc0);
            acc1 = MFMA16(af10, b0, zero4);
            acc1 = MFMA16(af11, b1, acc1);
            acc1 = MFMA16(af12, b2, acc1);
            acc2 = MFMA16(af20, b0, zero4);
            acc2 = MFMA16(af21, b1, acc2);
            acc2 = MFMA16(af22, b2, acc2);
            acc3 = MFMA16(af30, b0, zero4);
            acc3 = MFMA16(af31, b1, acc3);
            acc3 = MFMA16(af32, b2, acc3);
            acc4 = MFMA16(af40, b0, zero4);
            acc4 = MFMA16(af41, b1, acc4);
            acc4 = MFMA16(af42, b2, acc4);
            acc5 = MFMA16(af50, b0, zero4);
            acc5 = MFMA16(af51, b1, acc5);
            acc5 = MFMA16(af52, b2, acc5);
            if (wv == 3) {
                accy = MFMA16(afy0, b0, zero4);
                accy = MFMA16(afy1, b1, accy);
                accy = MFMA16(afy2, b2, accy);
                if (lane == 0 && it > 0)
                    y_buf[grp][((it - 1) >> 7) & 1][(it - 1) & (CHUNK - 1)] =
                        accy.x + bout;
            }
        }

        // ring flush: chunk [it-1-CHUNK, it-1) complete; wv==0, lanes 0..31
        if ((it & (CHUNK - 1)) == 1 && it > 1 && wv == 0 && lane < 32) {
            const int base = it - 1 - CHUNK;
            const int pb = (base >> 7) & 1;
            const f32x4 v =
                *reinterpret_cast<const f32x4*>(&y_buf[grp][pb][lane * 4]);
            *reinterpret_cast<f32x4*>(&yrow[base + lane * 4]) = v;
        }

        if (it < T_LEN) {
            f32x4 g4 = acc0;
            if (sel == 1) g4 = acc1;
            if (sel == 2) g4 = acc2;
            if (sel == 3) g4 = acc3;
            if (sel == 4) g4 = acc4;
            if (sel == 5) g4 = acc5;
            const float s0 = g4.x + fmaf(x_cur, wih_i, bias_i);
            const float s1 = g4.y + fmaf(x_cur, wih_f, bias_f);
            const float s2 = g4.z + fmaf(x_cur, wih_g, bias_g);
            const float s3 = g4.w + fmaf(x_cur, wih_o, bias_o);
            const float ig = sig2(s0);
            const float fg = sig2(s1);
            const float gg = tanh2(s2);
            const float og = sig2(s3);
            c = fmaf(fg, c, ig * gg);
            const float h = og * tanh2(2.0f * LOG2E * c);
            if (m < 6) h_s[grp][p ^ 1][cell] = (_Float16)h;
        }
        __syncthreads();  // h_s[.][p^1] + y_buf ready
    }
}

extern "C" void kernel_launch(void* const* d_in, const int* in_sizes, int n_in,
                              void* d_out, int out_size, void* d_ws, size_t ws_size,
                              hipStream_t stream) {
    const float* x     = (const float*)d_in[0];
    const float* w_ih  = (const float*)d_in[1];
    const float* w_hh  = (const float*)d_in[2];
    const float* b_ih  = (const float*)d_in[3];
    const float* b_hh  = (const float*)d_in[4];
    const float* w_out = (const float*)d_in[5];
    const float* b_out = (const float*)d_in[6];
    float* y = (float*)d_out;

    const int NBLK = 64;  // 2 batches per block
    lstm_mfma6_kernel<<<dim3(NBLK), dim3(NTHR), 0, stream>>>(
        x, w_ih, w_hh, b_ih, b_hh, w_out, b_out, y);
}